// Round 3
// baseline (604.326 us; speedup 1.0000x reference)
//
#include <hip/hip_runtime.h>
#include <hip/hip_bf16.h>
#include <stdint.h>

// Problem constants
#define B_   1024
#define L_   50
#define D_   128
#define NV_  8
#define NH_  16
#define KFC  1824   // NV*D + NH*L

typedef __bf16 bf16x8 __attribute__((ext_vector_type(8)));
typedef float  f32x4  __attribute__((ext_vector_type(4)));

static __device__ __forceinline__ bf16x8 as_bf16x8(uint4 u) {
  return __builtin_bit_cast(bf16x8, u);
}

// round-to-nearest-even f32 -> bf16 bits
static __device__ __forceinline__ unsigned short f2b(float x) {
  unsigned u = __float_as_uint(x);
  return (unsigned short)((u + 0x7FFFu + ((u >> 16) & 1u)) >> 16);
}

// ---- workspace layout (bytes) ----
// [0, OV)              : o buffer, B x 1824 f32 (o_v | o_h), memset 0 each launch
// [EOFF, EOFF+ESZ)     : E bf16, [b][ks(4)][row(50)][32 bf16]  (12800 B/b)
// [W2OFF, W2OFF+W2SZ)  : repacked conv weights: [pair p=T(i)+j][ks(4)][64 lanes x 16B]
#define OV_BYTES  ((size_t)B_ * KFC * 4)                  //  7,471,104
#define EOFF      (OV_BYTES)
#define ESZ       ((size_t)B_ * 4 * 50 * 64)              // 13,107,200
#define W2OFF     (EOFF + ESZ)
#define W2SZ      ((size_t)1275 * 4096)                   //  5,222,400
#define NEED_FULL (W2OFF + W2SZ)                          // 25,800,704

// ======================= kernel P: P_u copy -> out[:, 128:256]
__global__ void ck_kP(const int* __restrict__ uids, const float* __restrict__ uemb,
                      float* __restrict__ out) {
  int b = blockIdx.x, d = threadIdx.x;  // 128 threads
  out[(size_t)b * 256 + 128 + d] = uemb[(size_t)uids[b] * D_ + d];
}

// degenerate fallback (only if ws too small)
__global__ void ck_kZ(float* __restrict__ out) {
  int i = blockIdx.x * 256 + threadIdx.x;
  int b = i >> 7, d = i & 127;
  out[(size_t)b * 256 + d] = 0.f;
}

// ======================= kernel A: gather E -> bf16 (ks-major quarters, 50 rows)
__global__ void ck_kA(const int* __restrict__ item_seq, const float* __restrict__ item_emb,
                      char* __restrict__ ws) {
  int b = blockIdx.x, tid = threadIdx.x;
  __shared__ int sidx[L_];
  if (tid < L_) sidx[tid] = item_seq[b * L_ + tid];
  __syncthreads();
  char* eg = ws + EOFF + (size_t)b * 12800;
  #pragma unroll
  for (int it = 0; it < 4; ++it) {
    int c = it * 256 + tid;
    int ks = c >> 8, row = (c >> 2) & 63, g = c & 3;
    if (row < L_) {
      const float* src = item_emb + (size_t)sidx[row] * D_ + ks * 32 + g * 8;
      float4 f0 = *(const float4*)(src);
      float4 f1 = *(const float4*)(src + 4);
      uint4 val;
      val.x = f2b(f0.x) | ((unsigned)f2b(f0.y) << 16);
      val.y = f2b(f0.z) | ((unsigned)f2b(f0.w) << 16);
      val.z = f2b(f1.x) | ((unsigned)f2b(f1.y) << 16);
      val.w = f2b(f1.z) | ((unsigned)f2b(f1.w) << 16);
      *(uint4*)(eg + ks * 3200 + row * 64 + g * 16) = val;
    }
  }
}

// ======================= kernel W2: repack hconv_w -> B-frag-ready bf16
// W2[p = i(i+1)/2 + j][ks][lane*16B], lane l: n = l&15, d = ks*32 + (l>>4)*8 ..+8
__global__ void ck_kW2(const float* __restrict__ hw, char* __restrict__ ws) {
  int p = blockIdx.x, tid = threadIdx.x;     // 1275 blocks x 256
  int ks = tid >> 6, l = tid & 63;
  int n = l & 15, gq = l >> 4;
  int i = (int)((sqrtf(8.0f * (float)p + 1.0f) - 1.0f) * 0.5f);
  while ((i + 1) * (i + 2) / 2 <= p) ++i;
  while (i * (i + 1) / 2 > p) --i;
  int j = p - i * (i + 1) / 2;
  const float* src = hw + ((size_t)(i * 16 + n) * 50 + j) * 128 + ks * 32 + gq * 8;
  float4 f0 = *(const float4*)(src);
  float4 f1 = *(const float4*)(src + 4);
  uint4 v;
  v.x = f2b(f0.x) | ((unsigned)f2b(f0.y) << 16);
  v.y = f2b(f0.z) | ((unsigned)f2b(f0.w) << 16);
  v.z = f2b(f1.x) | ((unsigned)f2b(f1.y) << 16);
  v.w = f2b(f1.z) | ((unsigned)f2b(f1.w) << 16);
  *(uint4*)(ws + W2OFF + (size_t)p * 4096 + tid * 16) = v;
}

// ======================= kernel B: o_v[b,v,d] = sum_l E[b,l,d]*vf[l,v]  (f32)
__global__ void ck_kB(const int* __restrict__ item_seq, const float* __restrict__ item_emb,
                      const float* __restrict__ vf, char* __restrict__ ws) {
  int b = blockIdx.x, tid = threadIdx.x;
  __shared__ float E[L_][D_];
  __shared__ float VF[L_][NV_];
  __shared__ int sidx[L_];
  if (tid < L_) sidx[tid] = item_seq[b * L_ + tid];
  for (int c = tid; c < L_ * NV_; c += 256) VF[c / NV_][c % NV_] = vf[c];
  __syncthreads();
  for (int c = tid; c < 1600; c += 256) {
    int l = c >> 5, ch = c & 31;
    *(float4*)&E[l][ch * 4] = *(const float4*)(item_emb + (size_t)sidx[l] * D_ + ch * 4);
  }
  __syncthreads();
  int d = tid & 127, half = tid >> 7;
  float acc[4] = {0.f, 0.f, 0.f, 0.f};
  for (int l = 0; l < L_; ++l) {
    float e = E[l][d];
    #pragma unroll
    for (int vv = 0; vv < 4; ++vv) acc[vv] += e * VF[l][half * 4 + vv];
  }
  float* o = (float*)ws + (size_t)b * KFC;
  #pragma unroll
  for (int vv = 0; vv < 4; ++vv) o[(half * 4 + vv) * D_ + d] = acc[vv];
}

// ======================= kernel C2: horizontal convs, M=batch formulation
// Block: 16 b's, 4 waves; each wave owns a cost-balanced slot of (i, t-window) items.
// E LDS: [16 b][51 rows][64B] stride 3280 (bank-quad-spread). W from global (repacked).
#define EB_STRIDE 3280
#define LDS_E     (16 * EB_STRIDE)   // 52480

template<int NT4>
__device__ __forceinline__ void proc_item(const char* lds, const char* bp0,
    int i, int t0, f32x4 (&acc)[16], int aoff) {
  uint4 breg[4];
  breg[0] = *(const uint4*)(bp0);
  breg[1] = (i >= 1) ? *(const uint4*)(bp0 + 4096)  : breg[0];
  breg[2] = (i >= 2) ? *(const uint4*)(bp0 + 8192)  : breg[0];
  breg[3] = (i >= 3) ? *(const uint4*)(bp0 + 12288) : breg[0];
  bf16x8 win[16];
  #pragma unroll
  for (int tt = 0; tt < 16; ++tt) {
    int s = t0 + tt; s = s > 50 ? 50 : s;
    win[tt] = as_bf16x8(*(const uint4*)(lds + aoff + s * 64));
  }
  for (int j0 = 0; j0 <= i; j0 += 16) {
    #pragma unroll
    for (int u = 0; u < 16; ++u) {
      int j = j0 + u;
      if (j <= i) {
        bf16x8 bfr = as_bf16x8(breg[u & 3]);
        #pragma unroll
        for (int tt = 0; tt < NT4 && tt < 4; ++tt)
          acc[tt] = __builtin_amdgcn_mfma_f32_16x16x32_bf16(win[(u + tt) & 15], bfr, acc[tt], 0, 0, 0);
        int sn = t0 + j + 16; sn = sn > 50 ? 50 : sn;
        win[u] = as_bf16x8(*(const uint4*)(lds + aoff + sn * 64));  // slide window
        #pragma unroll
        for (int tt = 4; tt < NT4; ++tt)
          acc[tt] = __builtin_amdgcn_mfma_f32_16x16x32_bf16(win[(u + tt) & 15], bfr, acc[tt], 0, 0, 0);
        if (j + 4 <= i) breg[u & 3] = *(const uint4*)(bp0 + (size_t)(j + 4) * 4096);
      }
    }
  }
}

__device__ __forceinline__ void run_item(const char* lds, const char* W2, int ks,
    int enc, f32x4 (&acc)[16], int aoff, int lane) {
  int i = enc & 0xff, t0 = (enc >> 8) & 0xff, nt4 = (enc >> 24) & 0xff;
  const char* bp0 = W2 + (size_t)(i * (i + 1) / 2) * 4096 + ks * 1024 + lane * 16;
  switch (nt4 >> 2) {
    case 1:  proc_item<4> (lds, bp0, i, t0, acc, aoff); break;
    case 2:  proc_item<8> (lds, bp0, i, t0, acc, aoff); break;
    case 3:  proc_item<12>(lds, bp0, i, t0, acc, aoff); break;
    default: proc_item<16>(lds, bp0, i, t0, acc, aoff); break;
  }
}

__device__ __forceinline__ void epi_item(float* o, const float* hb, int b0,
    int enc, f32x4 (&acc)[16], int lane) {
  int i = enc & 0xff, nt = (enc >> 16) & 0xff;
  int r = lane & 15, gq = lane >> 4;
  float bias = hb[i * 16 + r];
  #pragma unroll
  for (int e = 0; e < 4; ++e) {
    float m = 0.f;
    #pragma unroll
    for (int tt = 0; tt < 16; ++tt)
      if (tt < nt) m = fmaxf(m, fmaxf(acc[tt][e] + bias, 0.f));
    atomicMax((unsigned*)&o[(size_t)(b0 + gq * 4 + e) * KFC + 1024 + i * 16 + r],
              __float_as_uint(m));
  }
}

__launch_bounds__(256, 2)
__global__ void ck_kC2(const float* __restrict__ hconv_b, char* __restrict__ ws) {
  __shared__ char lds[LDS_E + 512];
  int* litems = (int*)(lds + LDS_E);         // [4][24]
  int* lnit   = (int*)(lds + LDS_E + 384);   // [4]
  int tid = threadIdx.x;
  int wv = tid >> 6, lane = tid & 63;
  int r = lane & 15, gq = lane >> 4;
  int b0 = (int)blockIdx.x * 16;
  int myslot = (int)blockIdx.y * 4 + wv;
  int aoff = r * EB_STRIDE + gq * 16;

  // ---- cost-balanced item scan (TOTAL cost = 28236, 32 slots) ----
  {
    unsigned cum = 0; int cnt = 0;
    for (int i = 0; i < 50; ++i) {
      int nw = (65 - i) >> 4;                  // ceil((50-i)/16)
      int ntb = 50 - i - 16 * (nw - 1);
      for (int w = 0; w < nw; ++w) {
        int nt = w ? 16 : ntb;
        int t0 = w ? ntb + 16 * (w - 1) : 0;
        int nt4 = (nt + 3) & ~3;
        int slot = (int)((float)cum * (32.0f / 28236.0f));
        cum += (unsigned)((i + 1) * nt4 + 40);
        if (slot == myslot) {
          if (lane == 0 && cnt < 24)
            litems[wv * 24 + cnt] = i | (t0 << 8) | (nt << 16) | (nt4 << 24);
          ++cnt;
        }
      }
    }
    if (lane == 0) lnit[wv] = cnt > 24 ? 24 : cnt;
  }
  __syncthreads();
  int R = 0;
  #pragma unroll
  for (int k = 0; k < 4; ++k) { int q = (lnit[k] + 1) >> 1; R = R > q ? R : q; }

  const char* EG = ws + EOFF;
  const char* W2 = ws + W2OFF;
  float* o = (float*)ws;

  for (int rd = 0; rd < R; ++rd) {
    int nI = lnit[wv];
    int eA = (2 * rd     < nI) ? litems[wv * 24 + 2 * rd]     : -1;
    int eB = (2 * rd + 1 < nI) ? litems[wv * 24 + 2 * rd + 1] : -1;
    f32x4 acc0[16], acc1[16];
    #pragma unroll
    for (int t = 0; t < 16; ++t) {
      acc0[t][0]=0.f; acc0[t][1]=0.f; acc0[t][2]=0.f; acc0[t][3]=0.f;
      acc1[t][0]=0.f; acc1[t][1]=0.f; acc1[t][2]=0.f; acc1[t][3]=0.f;
    }
    for (int ks = 0; ks < 4; ++ks) {
      __syncthreads();
      // stage E d-quarter: 16 b x 50 rows x 64B, conflict-free stride 3280
      if (tid < 200) {
        #pragma unroll
        for (int bi = 0; bi < 16; ++bi)
          *(uint4*)(lds + bi * EB_STRIDE + tid * 16) =
            *(const uint4*)(EG + (size_t)(b0 + bi) * 12800 + ks * 3200 + tid * 16);
      }
      __syncthreads();
      if (eA >= 0) run_item(lds, W2, ks, eA, acc0, aoff, lane);
      if (eB >= 0) run_item(lds, W2, ks, eB, acc1, aoff, lane);
    }
    if (eA >= 0) epi_item(o, hconv_b, b0, eA, acc0, lane);
    if (eB >= 0) epi_item(o, hconv_b, b0, eB, acc1, lane);
  }
}

// ======================= kernel D: FC (full K) + bias + relu -> out[:, :128]
__launch_bounds__(256)
__global__ void ck_kD(const float* __restrict__ fc_w, const float* __restrict__ fc_b,
                      const char* __restrict__ ws, float* __restrict__ out) {
  __shared__ char ldsD[5120];  // A [64 rows][64B] @0 ; B [16 n][64B] @4096
  int b0 = blockIdx.x * 64, n0 = blockIdx.y * 16;
  int tid = threadIdx.x, w = tid >> 6, lane = tid & 63, r = lane & 15, gq = lane >> 4;
  const float* o = (const float*)ws;

  f32x4 acc; acc[0] = 0.f; acc[1] = 0.f; acc[2] = 0.f; acc[3] = 0.f;

  int rl = tid >> 2, ch = tid & 3;
  const float* asrc = o + (size_t)(b0 + rl) * KFC + ch * 8;
  int kk = tid >> 3, nn = tid & 7;

  float4 fa0 = *(const float4*)(asrc);
  float4 fa1 = *(const float4*)(asrc + 4);
  float fb0 = fc_w[(size_t)kk * D_ + n0 + nn];
  float fb1 = fc_w[(size_t)kk * D_ + n0 + nn + 8];

  int arow_off = rl * 64 + ((ch ^ (rl & 3)) << 4);
  int rloc = w * 16 + r;
  int ard = rloc * 64 + ((gq ^ (rloc & 3)) << 4);
  int brd = 4096 + r * 64 + ((gq ^ (r & 3)) << 4);

  for (int s = 0; s < 57; ++s) {
    __syncthreads();
    {
      uint4 v;
      v.x = f2b(fa0.x) | ((unsigned)f2b(fa0.y) << 16);
      v.y = f2b(fa0.z) | ((unsigned)f2b(fa0.w) << 16);
      v.z = f2b(fa1.x) | ((unsigned)f2b(fa1.y) << 16);
      v.w = f2b(fa1.z) | ((unsigned)f2b(fa1.w) << 16);
      *(uint4*)(ldsD + arow_off) = v;
      *(unsigned short*)(ldsD + 4096 + nn * 64 + (((kk >> 3) ^ (nn & 3)) << 4) + (kk & 7) * 2) = f2b(fb0);
      *(unsigned short*)(ldsD + 4096 + (nn + 8) * 64 + (((kk >> 3) ^ ((nn + 8) & 3)) << 4) + (kk & 7) * 2) = f2b(fb1);
    }
    __syncthreads();
    if (s + 1 < 57) {
      int kb = (s + 1) * 32;
      fa0 = *(const float4*)(asrc + kb);
      fa1 = *(const float4*)(asrc + kb + 4);
      fb0 = fc_w[(size_t)(kb + kk) * D_ + n0 + nn];
      fb1 = fc_w[(size_t)(kb + kk) * D_ + n0 + nn + 8];
    }
    bf16x8 a   = as_bf16x8(*(const uint4*)(ldsD + ard));
    bf16x8 bfr = as_bf16x8(*(const uint4*)(ldsD + brd));
    acc = __builtin_amdgcn_mfma_f32_16x16x32_bf16(a, bfr, acc, 0, 0, 0);
  }

  float bias = fc_b[n0 + r];
  #pragma unroll
  for (int e = 0; e < 4; ++e) {
    int row = b0 + w * 16 + gq * 4 + e;
    out[(size_t)row * 256 + n0 + r] = fmaxf(acc[e] + bias, 0.f);
  }
}

extern "C" void kernel_launch(void* const* d_in, const int* in_sizes, int n_in,
                              void* d_out, int out_size, void* d_ws, size_t ws_size,
                              hipStream_t stream) {
  const int*   user_ids = (const int*)d_in[0];
  const int*   item_seq = (const int*)d_in[1];
  const float* user_emb = (const float*)d_in[2];
  const float* item_emb = (const float*)d_in[3];
  const float* vfilter  = (const float*)d_in[4];
  const float* hconv_w  = (const float*)d_in[5];
  const float* hconv_b  = (const float*)d_in[6];
  const float* fc_w     = (const float*)d_in[7];
  const float* fc_b     = (const float*)d_in[8];
  float* out = (float*)d_out;
  char*  ws  = (char*)d_ws;

  ck_kP<<<dim3(B_), dim3(128), 0, stream>>>(user_ids, user_emb, out);

  if (ws_size < NEED_FULL) {
    ck_kZ<<<dim3(512), dim3(256), 0, stream>>>(out);
    return;
  }

  hipMemsetAsync(ws, 0, OV_BYTES, stream);  // atomicMax identity (all outputs >= 0)

  ck_kA<<<dim3(B_), dim3(256), 0, stream>>>(item_seq, item_emb, ws);
  ck_kW2<<<dim3(1275), dim3(256), 0, stream>>>(hconv_w, ws);
  ck_kB<<<dim3(B_), dim3(256), 0, stream>>>(item_seq, item_emb, vfilter, ws);
  ck_kC2<<<dim3(64, 8), dim3(256), 0, stream>>>(hconv_b, ws);
  ck_kD<<<dim3(16, 8), dim3(256), 0, stream>>>(fc_w, fc_b, ws, out);
}

// Round 4
// 352.405 us; speedup vs baseline: 1.7149x; 1.7149x over previous
//
#include <hip/hip_runtime.h>
#include <hip/hip_bf16.h>
#include <stdint.h>

// Problem constants
#define B_   1024
#define L_   50
#define D_   128
#define NV_  8
#define NH_  16
#define KFC  1824   // NV*D + NH*L

typedef __bf16 bf16x8 __attribute__((ext_vector_type(8)));
typedef float  f32x4  __attribute__((ext_vector_type(4)));

static __device__ __forceinline__ bf16x8 as_bf16x8(uint4 u) {
  return __builtin_bit_cast(bf16x8, u);
}

// round-to-nearest-even f32 -> bf16 bits
static __device__ __forceinline__ unsigned short f2b(float x) {
  unsigned u = __float_as_uint(x);
  return (unsigned short)((u + 0x7FFFu + ((u >> 16) & 1u)) >> 16);
}

// ---- workspace layout (bytes) ----
// [0, OV)              : o buffer, B x 1824 f32 (o_v | o_h), memset 0 each launch
// [EOFF, EOFF+ESZ)     : E bf16, [b][ks(4)][row(50)][32 bf16]  (12800 B/b)
// [W2OFF, W2OFF+W2SZ)  : repacked conv weights: [pair p=T(i)+j][ks(4)][64 lanes x 16B]
#define OV_BYTES  ((size_t)B_ * KFC * 4)                  //  7,471,104
#define EOFF      (OV_BYTES)
#define ESZ       ((size_t)B_ * 4 * 50 * 64)              // 13,107,200
#define W2OFF     (EOFF + ESZ)
#define W2SZ      ((size_t)1275 * 4096)                   //  5,222,400
#define NEED_FULL (W2OFF + W2SZ)                          // 25,800,704

// ======================= kernel P: P_u copy -> out[:, 128:256]
__global__ void ck_kP(const int* __restrict__ uids, const float* __restrict__ uemb,
                      float* __restrict__ out) {
  int b = blockIdx.x, d = threadIdx.x;  // 128 threads
  out[(size_t)b * 256 + 128 + d] = uemb[(size_t)uids[b] * D_ + d];
}

// degenerate fallback (only if ws too small)
__global__ void ck_kZ(float* __restrict__ out) {
  int i = blockIdx.x * 256 + threadIdx.x;
  int b = i >> 7, d = i & 127;
  out[(size_t)b * 256 + d] = 0.f;
}

// ======================= kernel A: gather E -> bf16 (ks-major quarters, 50 rows)
__global__ void ck_kA(const int* __restrict__ item_seq, const float* __restrict__ item_emb,
                      char* __restrict__ ws) {
  int b = blockIdx.x, tid = threadIdx.x;
  __shared__ int sidx[L_];
  if (tid < L_) sidx[tid] = item_seq[b * L_ + tid];
  __syncthreads();
  char* eg = ws + EOFF + (size_t)b * 12800;
  #pragma unroll
  for (int it = 0; it < 4; ++it) {
    int c = it * 256 + tid;
    int ks = c >> 8, row = (c >> 2) & 63, g = c & 3;
    if (row < L_) {
      const float* src = item_emb + (size_t)sidx[row] * D_ + ks * 32 + g * 8;
      float4 f0 = *(const float4*)(src);
      float4 f1 = *(const float4*)(src + 4);
      uint4 val;
      val.x = f2b(f0.x) | ((unsigned)f2b(f0.y) << 16);
      val.y = f2b(f0.z) | ((unsigned)f2b(f0.w) << 16);
      val.z = f2b(f1.x) | ((unsigned)f2b(f1.y) << 16);
      val.w = f2b(f1.z) | ((unsigned)f2b(f1.w) << 16);
      *(uint4*)(eg + ks * 3200 + row * 64 + g * 16) = val;
    }
  }
}

// ======================= kernel W2: repack hconv_w -> B-frag-ready bf16
// W2[p = i(i+1)/2 + j][ks][lane*16B], lane l: n = l&15, d = ks*32 + (l>>4)*8 ..+8
__global__ void ck_kW2(const float* __restrict__ hw, char* __restrict__ ws) {
  int p = blockIdx.x, tid = threadIdx.x;     // 1275 blocks x 256
  int ks = tid >> 6, l = tid & 63;
  int n = l & 15, gq = l >> 4;
  int i = (int)((sqrtf(8.0f * (float)p + 1.0f) - 1.0f) * 0.5f);
  while ((i + 1) * (i + 2) / 2 <= p) ++i;
  while (i * (i + 1) / 2 > p) --i;
  int j = p - i * (i + 1) / 2;
  const float* src = hw + ((size_t)(i * 16 + n) * 50 + j) * 128 + ks * 32 + gq * 8;
  float4 f0 = *(const float4*)(src);
  float4 f1 = *(const float4*)(src + 4);
  uint4 v;
  v.x = f2b(f0.x) | ((unsigned)f2b(f0.y) << 16);
  v.y = f2b(f0.z) | ((unsigned)f2b(f0.w) << 16);
  v.z = f2b(f1.x) | ((unsigned)f2b(f1.y) << 16);
  v.w = f2b(f1.z) | ((unsigned)f2b(f1.w) << 16);
  *(uint4*)(ws + W2OFF + (size_t)p * 4096 + tid * 16) = v;
}

// ======================= kernel B: o_v[b,v,d] = sum_l E[b,l,d]*vf[l,v]  (f32)
__global__ void ck_kB(const int* __restrict__ item_seq, const float* __restrict__ item_emb,
                      const float* __restrict__ vf, char* __restrict__ ws) {
  int b = blockIdx.x, tid = threadIdx.x;
  __shared__ float E[L_][D_];
  __shared__ float VF[L_][NV_];
  __shared__ int sidx[L_];
  if (tid < L_) sidx[tid] = item_seq[b * L_ + tid];
  for (int c = tid; c < L_ * NV_; c += 256) VF[c / NV_][c % NV_] = vf[c];
  __syncthreads();
  for (int c = tid; c < 1600; c += 256) {
    int l = c >> 5, ch = c & 31;
    *(float4*)&E[l][ch * 4] = *(const float4*)(item_emb + (size_t)sidx[l] * D_ + ch * 4);
  }
  __syncthreads();
  int d = tid & 127, half = tid >> 7;
  float acc[4] = {0.f, 0.f, 0.f, 0.f};
  for (int l = 0; l < L_; ++l) {
    float e = E[l][d];
    #pragma unroll
    for (int vv = 0; vv < 4; ++vv) acc[vv] += e * VF[l][half * 4 + vv];
  }
  float* o = (float*)ws + (size_t)b * KFC;
  #pragma unroll
  for (int vv = 0; vv < 4; ++vv) o[(half * 4 + vv) * D_ + d] = acc[vv];
}

// ======================= kernel C3: horizontal convs, M=batch, sliding window
// Block: 16 b's, 4 waves; ONE item per wave per round (no spills), snake schedule.
// E LDS: [16 b][50 rows + clamp row][64B] stride 3280 (bank-quad-uniform).
#define EB_STRIDE 3280
#define LDS_E     (16 * EB_STRIDE)   // 52480

template<int NT4>
__device__ __forceinline__ void proc_item(const char* lds, const char* bp0,
    int i, int t0, f32x4 (&acc)[16], int aoff) {
  uint4 breg[4];
  breg[0] = *(const uint4*)(bp0);
  breg[1] = (i >= 1) ? *(const uint4*)(bp0 + 4096)  : breg[0];
  breg[2] = (i >= 2) ? *(const uint4*)(bp0 + 8192)  : breg[0];
  breg[3] = (i >= 3) ? *(const uint4*)(bp0 + 12288) : breg[0];
  bf16x8 win[16];
  #pragma unroll
  for (int tt = 0; tt < 16; ++tt) {
    int s = t0 + tt; s = s > 50 ? 50 : s;
    win[tt] = as_bf16x8(*(const uint4*)(lds + aoff + s * 64));
  }
  for (int j0 = 0; j0 <= i; j0 += 16) {
    #pragma unroll
    for (int u = 0; u < 16; ++u) {
      int j = j0 + u;
      if (j <= i) {
        bf16x8 bfr = as_bf16x8(breg[u & 3]);
        #pragma unroll
        for (int tt = 0; tt < NT4 && tt < 4; ++tt)
          acc[tt] = __builtin_amdgcn_mfma_f32_16x16x32_bf16(win[(u + tt) & 15], bfr, acc[tt], 0, 0, 0);
        int sn = t0 + j + 16; sn = sn > 50 ? 50 : sn;
        win[u] = as_bf16x8(*(const uint4*)(lds + aoff + sn * 64));  // slide window
        #pragma unroll
        for (int tt = 4; tt < NT4; ++tt)
          acc[tt] = __builtin_amdgcn_mfma_f32_16x16x32_bf16(win[(u + tt) & 15], bfr, acc[tt], 0, 0, 0);
        if (j + 4 <= i) breg[u & 3] = *(const uint4*)(bp0 + (size_t)(j + 4) * 4096);
      }
    }
  }
}

__device__ __forceinline__ void run_item(const char* lds, const char* W2, int ks,
    int enc, f32x4 (&acc)[16], int aoff, int lane) {
  int i = enc & 0xff, t0 = (enc >> 8) & 0xff, nt4 = (enc >> 24) & 0xff;
  const char* bp0 = W2 + (size_t)(i * (i + 1) / 2) * 4096 + ks * 1024 + lane * 16;
  switch (nt4 >> 2) {
    case 1:  proc_item<4> (lds, bp0, i, t0, acc, aoff); break;
    case 2:  proc_item<8> (lds, bp0, i, t0, acc, aoff); break;
    case 3:  proc_item<12>(lds, bp0, i, t0, acc, aoff); break;
    default: proc_item<16>(lds, bp0, i, t0, acc, aoff); break;
  }
}

__device__ __forceinline__ void epi_item(float* o, const float* hb, int b0,
    int enc, f32x4 (&acc)[16], int lane) {
  int i = enc & 0xff, nt = (enc >> 16) & 0xff;
  int r = lane & 15, gq = lane >> 4;
  float bias = hb[i * 16 + r];
  #pragma unroll
  for (int e = 0; e < 4; ++e) {
    float m = 0.f;
    #pragma unroll
    for (int tt = 0; tt < 16; ++tt)
      if (tt < nt) m = fmaxf(m, fmaxf(acc[tt][e] + bias, 0.f));
    atomicMax((unsigned*)&o[(size_t)(b0 + gq * 4 + e) * KFC + 1024 + i * 16 + r],
              __float_as_uint(m));
  }
}

__launch_bounds__(256, 2)
__global__ void ck_kC3(const float* __restrict__ hconv_b, char* __restrict__ ws) {
  __shared__ char lds[LDS_E + 1408];
  int* wenc  = (int*)(lds + LDS_E);          // 104 ints
  int* wcost = (int*)(lds + LDS_E + 448);    // 104 ints
  int* sched = (int*)(lds + LDS_E + 896);    // 32 slots x 4 rounds
  int tid = threadIdx.x;
  int wv = tid >> 6, lane = tid & 63;
  int r = lane & 15, gq = lane >> 4;
  int b0 = (int)blockIdx.x * 16;
  int slot = (int)blockIdx.y * 4 + wv;
  int aoff = r * EB_STRIDE + gq * 16;

  // ---- build snake schedule: 104 windows ranked by cost, dealt to 32 slots x 4 rounds
  if (tid < 128) sched[tid] = -1;
  if (tid < 104) {
    int idx = tid, i, nw = 1;
    for (i = 0; i < 50; ++i) {
      nw = (65 - i) >> 4;                    // ceil((50-i)/16)
      if (idx < nw) break;
      idx -= nw;
    }
    int ntb = 50 - i - 16 * (nw - 1);
    int nt = idx ? 16 : ntb;
    int t0 = idx ? ntb + 16 * (idx - 1) : 0;
    int nt4 = (nt + 3) & ~3;
    wenc[tid]  = i | (t0 << 8) | (nt << 16) | (nt4 << 24);
    wcost[tid] = (((i + 1) * nt4) << 7) + tid;   // unique keys
  }
  __syncthreads();
  if (tid < 104) {
    int c = wcost[tid], rank = 0;
    for (int u = 0; u < 104; ++u) rank += (wcost[u] > c) ? 1 : 0;
    int rnd = rank >> 5, pos = rank & 31;
    int sl = (rnd & 1) ? (31 - pos) : pos;     // snake: equal-cost rounds
    sched[sl * 4 + rnd] = wenc[tid];
  }
  __syncthreads();

  const char* EG = ws + EOFF;
  const char* W2 = ws + W2OFF;
  float* o = (float*)ws;

  for (int rd = 0; rd < 4; ++rd) {
    int enc = sched[slot * 4 + rd];
    f32x4 acc[16];
    #pragma unroll
    for (int t = 0; t < 16; ++t) {
      acc[t][0] = 0.f; acc[t][1] = 0.f; acc[t][2] = 0.f; acc[t][3] = 0.f;
    }
    for (int ks = 0; ks < 4; ++ks) {
      __syncthreads();
      // stage E d-quarter: 16 b x 50 rows x 64B, bank-quad-uniform stride
      if (tid < 200) {
        const char* ebase = EG + (size_t)b0 * 12800 + ks * 3200 + tid * 16;
        char* ldst = lds + tid * 16;
        #pragma unroll
        for (int bi = 0; bi < 16; ++bi)
          *(uint4*)(ldst + bi * EB_STRIDE) = *(const uint4*)(ebase + (size_t)bi * 12800);
      }
      __syncthreads();
      if (enc >= 0) run_item(lds, W2, ks, enc, acc, aoff, lane);
    }
    if (enc >= 0) epi_item(o, hconv_b, b0, enc, acc, lane);
  }
}

// ======================= kernel D: FC (full K) + bias + relu -> out[:, :128]
__launch_bounds__(256)
__global__ void ck_kD(const float* __restrict__ fc_w, const float* __restrict__ fc_b,
                      const char* __restrict__ ws, float* __restrict__ out) {
  __shared__ char ldsD[5120];  // A [64 rows][64B] @0 ; B [16 n][64B] @4096
  int b0 = blockIdx.x * 64, n0 = blockIdx.y * 16;
  int tid = threadIdx.x, w = tid >> 6, lane = tid & 63, r = lane & 15, gq = lane >> 4;
  const float* o = (const float*)ws;

  f32x4 acc; acc[0] = 0.f; acc[1] = 0.f; acc[2] = 0.f; acc[3] = 0.f;

  int rl = tid >> 2, ch = tid & 3;
  const float* asrc = o + (size_t)(b0 + rl) * KFC + ch * 8;
  int kk = tid >> 3, nn = tid & 7;

  float4 fa0 = *(const float4*)(asrc);
  float4 fa1 = *(const float4*)(asrc + 4);
  float fb0 = fc_w[(size_t)kk * D_ + n0 + nn];
  float fb1 = fc_w[(size_t)kk * D_ + n0 + nn + 8];

  int arow_off = rl * 64 + ((ch ^ (rl & 3)) << 4);
  int rloc = w * 16 + r;
  int ard = rloc * 64 + ((gq ^ (rloc & 3)) << 4);
  int brd = 4096 + r * 64 + ((gq ^ (r & 3)) << 4);

  for (int s = 0; s < 57; ++s) {
    __syncthreads();
    {
      uint4 v;
      v.x = f2b(fa0.x) | ((unsigned)f2b(fa0.y) << 16);
      v.y = f2b(fa0.z) | ((unsigned)f2b(fa0.w) << 16);
      v.z = f2b(fa1.x) | ((unsigned)f2b(fa1.y) << 16);
      v.w = f2b(fa1.z) | ((unsigned)f2b(fa1.w) << 16);
      *(uint4*)(ldsD + arow_off) = v;
      *(unsigned short*)(ldsD + 4096 + nn * 64 + (((kk >> 3) ^ (nn & 3)) << 4) + (kk & 7) * 2) = f2b(fb0);
      *(unsigned short*)(ldsD + 4096 + (nn + 8) * 64 + (((kk >> 3) ^ ((nn + 8) & 3)) << 4) + (kk & 7) * 2) = f2b(fb1);
    }
    __syncthreads();
    if (s + 1 < 57) {
      int kb = (s + 1) * 32;
      fa0 = *(const float4*)(asrc + kb);
      fa1 = *(const float4*)(asrc + kb + 4);
      fb0 = fc_w[(size_t)(kb + kk) * D_ + n0 + nn];
      fb1 = fc_w[(size_t)(kb + kk) * D_ + n0 + nn + 8];
    }
    bf16x8 a   = as_bf16x8(*(const uint4*)(ldsD + ard));
    bf16x8 bfr = as_bf16x8(*(const uint4*)(ldsD + brd));
    acc = __builtin_amdgcn_mfma_f32_16x16x32_bf16(a, bfr, acc, 0, 0, 0);
  }

  float bias = fc_b[n0 + r];
  #pragma unroll
  for (int e = 0; e < 4; ++e) {
    int row = b0 + w * 16 + gq * 4 + e;
    out[(size_t)row * 256 + n0 + r] = fmaxf(acc[e] + bias, 0.f);
  }
}

extern "C" void kernel_launch(void* const* d_in, const int* in_sizes, int n_in,
                              void* d_out, int out_size, void* d_ws, size_t ws_size,
                              hipStream_t stream) {
  const int*   user_ids = (const int*)d_in[0];
  const int*   item_seq = (const int*)d_in[1];
  const float* user_emb = (const float*)d_in[2];
  const float* item_emb = (const float*)d_in[3];
  const float* vfilter  = (const float*)d_in[4];
  const float* hconv_w  = (const float*)d_in[5];
  const float* hconv_b  = (const float*)d_in[6];
  const float* fc_w     = (const float*)d_in[7];
  const float* fc_b     = (const float*)d_in[8];
  float* out = (float*)d_out;
  char*  ws  = (char*)d_ws;

  ck_kP<<<dim3(B_), dim3(128), 0, stream>>>(user_ids, user_emb, out);

  if (ws_size < NEED_FULL) {
    ck_kZ<<<dim3(512), dim3(256), 0, stream>>>(out);
    return;
  }

  hipMemsetAsync(ws, 0, OV_BYTES, stream);  // atomicMax identity (all outputs >= 0)

  ck_kA<<<dim3(B_), dim3(256), 0, stream>>>(item_seq, item_emb, ws);
  ck_kW2<<<dim3(1275), dim3(256), 0, stream>>>(hconv_w, ws);
  ck_kB<<<dim3(B_), dim3(256), 0, stream>>>(item_seq, item_emb, vfilter, ws);
  ck_kC3<<<dim3(64, 8), dim3(256), 0, stream>>>(hconv_b, ws);
  ck_kD<<<dim3(16, 8), dim3(256), 0, stream>>>(fc_w, fc_b, ws, out);
}

// Round 5
// 163.634 us; speedup vs baseline: 3.6932x; 2.1536x over previous
//
#include <hip/hip_runtime.h>
#include <hip/hip_bf16.h>
#include <stdint.h>

// Problem constants
#define B_   1024
#define L_   50
#define D_   128
#define NV_  8
#define NH_  16
#define KFC  1824   // NV*D + NH*L

typedef __bf16 bf16x8 __attribute__((ext_vector_type(8)));
typedef float  f32x4  __attribute__((ext_vector_type(4)));

static __device__ __forceinline__ bf16x8 as_bf16x8(uint4 u) {
  return __builtin_bit_cast(bf16x8, u);
}

// round-to-nearest-even f32 -> bf16 bits
static __device__ __forceinline__ unsigned short f2b(float x) {
  unsigned u = __float_as_uint(x);
  return (unsigned short)((u + 0x7FFFu + ((u >> 16) & 1u)) >> 16);
}

// ---- workspace layout (bytes) ----
// [0, OV)              : o buffer, B x 1824 f32 (o_v | o_h), memset 0 each launch
// [EOFF, EOFF+ESZ)     : E bf16, [b][ks(4)][row(50)][32 bf16]  (12800 B/b)
// [W2OFF, W2OFF+W2SZ)  : repacked conv weights: [pair p=T(i)+j][ks(4)][64 lanes x 16B]
#define OV_BYTES  ((size_t)B_ * KFC * 4)                  //  7,471,104
#define EOFF      (OV_BYTES)
#define ESZ       ((size_t)B_ * 4 * 50 * 64)              // 13,107,200
#define W2OFF     (EOFF + ESZ)
#define W2SZ      ((size_t)1275 * 4096)                   //  5,222,400
#define NEED_FULL (W2OFF + W2SZ)                          // 25,800,704

// ======================= kernel P: P_u copy -> out[:, 128:256]
__global__ void ck_kP(const int* __restrict__ uids, const float* __restrict__ uemb,
                      float* __restrict__ out) {
  int b = blockIdx.x, d = threadIdx.x;  // 128 threads
  out[(size_t)b * 256 + 128 + d] = uemb[(size_t)uids[b] * D_ + d];
}

// degenerate fallback (only if ws too small)
__global__ void ck_kZ(float* __restrict__ out) {
  int i = blockIdx.x * 256 + threadIdx.x;
  int b = i >> 7, d = i & 127;
  out[(size_t)b * 256 + d] = 0.f;
}

// ======================= kernel A: gather E -> bf16 (ks-major quarters, 50 rows)
__global__ void ck_kA(const int* __restrict__ item_seq, const float* __restrict__ item_emb,
                      char* __restrict__ ws) {
  int b = blockIdx.x, tid = threadIdx.x;
  __shared__ int sidx[L_];
  if (tid < L_) sidx[tid] = item_seq[b * L_ + tid];
  __syncthreads();
  char* eg = ws + EOFF + (size_t)b * 12800;
  #pragma unroll
  for (int it = 0; it < 4; ++it) {
    int c = it * 256 + tid;
    int ks = c >> 8, row = (c >> 2) & 63, g = c & 3;
    if (row < L_) {
      const float* src = item_emb + (size_t)sidx[row] * D_ + ks * 32 + g * 8;
      float4 f0 = *(const float4*)(src);
      float4 f1 = *(const float4*)(src + 4);
      uint4 val;
      val.x = f2b(f0.x) | ((unsigned)f2b(f0.y) << 16);
      val.y = f2b(f0.z) | ((unsigned)f2b(f0.w) << 16);
      val.z = f2b(f1.x) | ((unsigned)f2b(f1.y) << 16);
      val.w = f2b(f1.z) | ((unsigned)f2b(f1.w) << 16);
      *(uint4*)(eg + ks * 3200 + row * 64 + g * 16) = val;
    }
  }
}

// ======================= kernel W2: repack hconv_w -> B-frag-ready bf16
// W2[p = i(i+1)/2 + j][ks][lane*16B], lane l: n = l&15, d = ks*32 + (l>>4)*8 ..+8
__global__ void ck_kW2(const float* __restrict__ hw, char* __restrict__ ws) {
  int p = blockIdx.x, tid = threadIdx.x;     // 1275 blocks x 256
  int ks = tid >> 6, l = tid & 63;
  int n = l & 15, gq = l >> 4;
  int i = (int)((sqrtf(8.0f * (float)p + 1.0f) - 1.0f) * 0.5f);
  while ((i + 1) * (i + 2) / 2 <= p) ++i;
  while (i * (i + 1) / 2 > p) --i;
  int j = p - i * (i + 1) / 2;
  const float* src = hw + ((size_t)(i * 16 + n) * 50 + j) * 128 + ks * 32 + gq * 8;
  float4 f0 = *(const float4*)(src);
  float4 f1 = *(const float4*)(src + 4);
  uint4 v;
  v.x = f2b(f0.x) | ((unsigned)f2b(f0.y) << 16);
  v.y = f2b(f0.z) | ((unsigned)f2b(f0.w) << 16);
  v.z = f2b(f1.x) | ((unsigned)f2b(f1.y) << 16);
  v.w = f2b(f1.z) | ((unsigned)f2b(f1.w) << 16);
  *(uint4*)(ws + W2OFF + (size_t)p * 4096 + tid * 16) = v;
}

// ======================= kernel B: o_v[b,v,d] = sum_l E[b,l,d]*vf[l,v]  (f32)
__global__ void ck_kB(const int* __restrict__ item_seq, const float* __restrict__ item_emb,
                      const float* __restrict__ vf, char* __restrict__ ws) {
  int b = blockIdx.x, tid = threadIdx.x;
  __shared__ float E[L_][D_];
  __shared__ float VF[L_][NV_];
  __shared__ int sidx[L_];
  if (tid < L_) sidx[tid] = item_seq[b * L_ + tid];
  for (int c = tid; c < L_ * NV_; c += 256) VF[c / NV_][c % NV_] = vf[c];
  __syncthreads();
  for (int c = tid; c < 1600; c += 256) {
    int l = c >> 5, ch = c & 31;
    *(float4*)&E[l][ch * 4] = *(const float4*)(item_emb + (size_t)sidx[l] * D_ + ch * 4);
  }
  __syncthreads();
  int d = tid & 127, half = tid >> 7;
  float acc[4] = {0.f, 0.f, 0.f, 0.f};
  for (int l = 0; l < L_; ++l) {
    float e = E[l][d];
    #pragma unroll
    for (int vv = 0; vv < 4; ++vv) acc[vv] += e * VF[l][half * 4 + vv];
  }
  float* o = (float*)ws + (size_t)b * KFC;
  #pragma unroll
  for (int vv = 0; vv < 4; ++vv) o[(half * 4 + vv) * D_ + d] = acc[vv];
}

// ======================= kernel C4: horizontal convs, M=batch, sliding window of 8
// Block: 512 threads (8 waves) sharing one 16-b E tile; grid (64 bx, 8 by) = 64 slots/bx.
// Per wave state: acc[8] + win[8] + breg[8] ~ 116 VGPR -> 4 waves/SIMD, no spill.
#define EB_STRIDE 3280
#define LDS_E     (16 * EB_STRIDE)   // 52480
#define NWIN      182
#define WENC_OFF  LDS_E
#define WCOST_OFF (LDS_E + 728)
#define SCHED_OFF (LDS_E + 1456)
#define LDS_TOT   (LDS_E + 1456 + 768)   // 54704

#define MFMA_BF16 __builtin_amdgcn_mfma_f32_16x16x32_bf16

template<int NT4>
__device__ __forceinline__ void proc_item(const char* lds, const char* bp0,
    int i, int t0, f32x4 (&acc)[8], int aoff) {
  bf16x8 win[8];
  #pragma unroll
  for (int q = 0; q < 8; ++q) {
    int s = t0 + q; s = s > 50 ? 50 : s;
    win[q] = as_bf16x8(*(const uint4*)(lds + aoff + s * 64));
  }
  uint4 breg[8];
  #pragma unroll
  for (int u = 0; u < 8; ++u)
    breg[u] = *(const uint4*)(bp0 + (size_t)(u <= i ? u : 0) * 4096);

  for (int j0 = 0; j0 <= i; j0 += 8) {
    #pragma unroll
    for (int u = 0; u < 8; ++u) {
      int j = j0 + u;
      if (j <= i) {
        bf16x8 bfr = as_bf16x8(breg[u]);
        acc[0] = MFMA_BF16(win[u], bfr, acc[0], 0, 0, 0);
        acc[1] = MFMA_BF16(win[(u + 1) & 7], bfr, acc[1], 0, 0, 0);
        acc[2] = MFMA_BF16(win[(u + 2) & 7], bfr, acc[2], 0, 0, 0);
        acc[3] = MFMA_BF16(win[(u + 3) & 7], bfr, acc[3], 0, 0, 0);
        int sn = t0 + j + 8; sn = sn > 50 ? 50 : sn;   // row 50 = don't-care pad
        win[u] = as_bf16x8(*(const uint4*)(lds + aoff + sn * 64));  // slide
        if (NT4 == 8) {
          acc[4] = MFMA_BF16(win[(u + 4) & 7], bfr, acc[4], 0, 0, 0);
          acc[5] = MFMA_BF16(win[(u + 5) & 7], bfr, acc[5], 0, 0, 0);
          acc[6] = MFMA_BF16(win[(u + 6) & 7], bfr, acc[6], 0, 0, 0);
          acc[7] = MFMA_BF16(win[(u + 7) & 7], bfr, acc[7], 0, 0, 0);
        }
        if (j + 8 <= i) breg[u] = *(const uint4*)(bp0 + (size_t)(j + 8) * 4096);
      }
    }
  }
}

__device__ __forceinline__ void run_item(const char* lds, const char* W2, int ks,
    int enc, f32x4 (&acc)[8], int aoff, int lane) {
  int i = enc & 0xff, t0 = (enc >> 8) & 0xff, nt4 = (enc >> 24) & 0xff;
  const char* bp0 = W2 + (size_t)(i * (i + 1) / 2) * 4096 + ks * 1024 + lane * 16;
  if (nt4 == 4) proc_item<4>(lds, bp0, i, t0, acc, aoff);
  else          proc_item<8>(lds, bp0, i, t0, acc, aoff);
}

__device__ __forceinline__ void epi_item(float* o, const float* hb, int b0,
    int enc, f32x4 (&acc)[8], int lane) {
  int i = enc & 0xff, nt = (enc >> 16) & 0xff;
  int r = lane & 15, gq = lane >> 4;
  float bias = hb[i * 16 + r];
  #pragma unroll
  for (int e = 0; e < 4; ++e) {
    float m = 0.f;
    #pragma unroll
    for (int tt = 0; tt < 8; ++tt)
      if (tt < nt) m = fmaxf(m, fmaxf(acc[tt][e] + bias, 0.f));
    atomicMax((unsigned*)&o[(size_t)(b0 + gq * 4 + e) * KFC + 1024 + i * 16 + r],
              __float_as_uint(m));
  }
}

__launch_bounds__(512, 4)
__global__ void ck_kC4(const float* __restrict__ hconv_b, char* __restrict__ ws) {
  __shared__ char lds[LDS_TOT];
  int* wenc  = (int*)(lds + WENC_OFF);    // 182 ints
  int* wcost = (int*)(lds + WCOST_OFF);   // 182 ints
  int* sched = (int*)(lds + SCHED_OFF);   // 64 slots x 3 rounds
  int tid = threadIdx.x;
  int wv = tid >> 6, lane = tid & 63;
  int r = lane & 15, gq = lane >> 4;
  int b0 = (int)blockIdx.x * 16;
  int slot = (int)blockIdx.y * 8 + wv;
  int aoff = r * EB_STRIDE + gq * 16;

  // ---- build snake schedule: 182 windows (t-blocks of 8) ranked by cost ----
  if (tid < 192) sched[tid] = -1;
  if (tid < NWIN) {
    int idx = tid, i, nw = 1;
    for (i = 0; i < 50; ++i) {
      nw = (57 - i) >> 3;                  // ceil((50-i)/8)
      if (idx < nw) break;
      idx -= nw;
    }
    int ntb = 50 - i - 8 * (nw - 1);
    int nt = idx ? 8 : ntb;
    int t0 = idx ? ntb + 8 * (idx - 1) : 0;
    int nt4 = (nt + 3) & ~3;
    wenc[tid]  = i | (t0 << 8) | (nt << 16) | (nt4 << 24);
    wcost[tid] = (((i + 1) * nt4) << 8) + tid;   // unique keys
  }
  __syncthreads();
  if (tid < NWIN) {
    int c = wcost[tid], rank = 0;
    for (int u = 0; u < NWIN; ++u) rank += (wcost[u] > c) ? 1 : 0;
    int rnd = rank >> 6, pos = rank & 63;
    int sl = (rnd & 1) ? (63 - pos) : pos;       // snake: equal-cost rounds
    sched[sl * 3 + rnd] = wenc[tid];
  }
  __syncthreads();

  const char* EG = ws + EOFF;
  const char* W2 = ws + W2OFF;
  float* o = (float*)ws;

  int sb = tid < 400 ? tid / 25 : 0;     // staging roles: b index, chunk
  int sm = tid < 400 ? tid % 25 : 0;

  for (int rd = 0; rd < 3; ++rd) {
    int enc = sched[slot * 3 + rd];
    f32x4 acc[8];
    #pragma unroll
    for (int t = 0; t < 8; ++t) {
      acc[t][0] = 0.f; acc[t][1] = 0.f; acc[t][2] = 0.f; acc[t][3] = 0.f;
    }
    for (int ks = 0; ks < 4; ++ks) {
      __syncthreads();
      // stage E d-quarter: 16 b x 50 rows x 64B (3200 uint4), 400 threads x 8
      if (tid < 400) {
        const char* src = EG + (size_t)(b0 + sb) * 12800 + ks * 3200 + sm * 16;
        char* dst = lds + sb * EB_STRIDE + sm * 16;
        #pragma unroll
        for (int q = 0; q < 8; ++q)
          *(uint4*)(dst + q * 400) = *(const uint4*)(src + q * 400);
      }
      __syncthreads();
      if (enc >= 0) run_item(lds, W2, ks, enc, acc, aoff, lane);
    }
    if (enc >= 0) epi_item(o, hconv_b, b0, enc, acc, lane);
  }
}

// ======================= kernel D: FC (full K) + bias + relu -> out[:, :128]
__launch_bounds__(256)
__global__ void ck_kD(const float* __restrict__ fc_w, const float* __restrict__ fc_b,
                      const char* __restrict__ ws, float* __restrict__ out) {
  __shared__ char ldsD[5120];  // A [64 rows][64B] @0 ; B [16 n][64B] @4096
  int b0 = blockIdx.x * 64, n0 = blockIdx.y * 16;
  int tid = threadIdx.x, w = tid >> 6, lane = tid & 63, r = lane & 15, gq = lane >> 4;
  const float* o = (const float*)ws;

  f32x4 acc; acc[0] = 0.f; acc[1] = 0.f; acc[2] = 0.f; acc[3] = 0.f;

  int rl = tid >> 2, ch = tid & 3;
  const float* asrc = o + (size_t)(b0 + rl) * KFC + ch * 8;
  int kk = tid >> 3, nn = tid & 7;

  float4 fa0 = *(const float4*)(asrc);
  float4 fa1 = *(const float4*)(asrc + 4);
  float fb0 = fc_w[(size_t)kk * D_ + n0 + nn];
  float fb1 = fc_w[(size_t)kk * D_ + n0 + nn + 8];

  int arow_off = rl * 64 + ((ch ^ (rl & 3)) << 4);
  int rloc = w * 16 + r;
  int ard = rloc * 64 + ((gq ^ (rloc & 3)) << 4);
  int brd = 4096 + r * 64 + ((gq ^ (r & 3)) << 4);

  for (int s = 0; s < 57; ++s) {
    __syncthreads();
    {
      uint4 v;
      v.x = f2b(fa0.x) | ((unsigned)f2b(fa0.y) << 16);
      v.y = f2b(fa0.z) | ((unsigned)f2b(fa0.w) << 16);
      v.z = f2b(fa1.x) | ((unsigned)f2b(fa1.y) << 16);
      v.w = f2b(fa1.z) | ((unsigned)f2b(fa1.w) << 16);
      *(uint4*)(ldsD + arow_off) = v;
      *(unsigned short*)(ldsD + 4096 + nn * 64 + (((kk >> 3) ^ (nn & 3)) << 4) + (kk & 7) * 2) = f2b(fb0);
      *(unsigned short*)(ldsD + 4096 + (nn + 8) * 64 + (((kk >> 3) ^ ((nn + 8) & 3)) << 4) + (kk & 7) * 2) = f2b(fb1);
    }
    __syncthreads();
    if (s + 1 < 57) {
      int kb = (s + 1) * 32;
      fa0 = *(const float4*)(asrc + kb);
      fa1 = *(const float4*)(asrc + kb + 4);
      fb0 = fc_w[(size_t)(kb + kk) * D_ + n0 + nn];
      fb1 = fc_w[(size_t)(kb + kk) * D_ + n0 + nn + 8];
    }
    bf16x8 a   = as_bf16x8(*(const uint4*)(ldsD + ard));
    bf16x8 bfr = as_bf16x8(*(const uint4*)(ldsD + brd));
    acc = __builtin_amdgcn_mfma_f32_16x16x32_bf16(a, bfr, acc, 0, 0, 0);
  }

  float bias = fc_b[n0 + r];
  #pragma unroll
  for (int e = 0; e < 4; ++e) {
    int row = b0 + w * 16 + gq * 4 + e;
    out[(size_t)row * 256 + n0 + r] = fmaxf(acc[e] + bias, 0.f);
  }
}

extern "C" void kernel_launch(void* const* d_in, const int* in_sizes, int n_in,
                              void* d_out, int out_size, void* d_ws, size_t ws_size,
                              hipStream_t stream) {
  const int*   user_ids = (const int*)d_in[0];
  const int*   item_seq = (const int*)d_in[1];
  const float* user_emb = (const float*)d_in[2];
  const float* item_emb = (const float*)d_in[3];
  const float* vfilter  = (const float*)d_in[4];
  const float* hconv_w  = (const float*)d_in[5];
  const float* hconv_b  = (const float*)d_in[6];
  const float* fc_w     = (const float*)d_in[7];
  const float* fc_b     = (const float*)d_in[8];
  float* out = (float*)d_out;
  char*  ws  = (char*)d_ws;

  ck_kP<<<dim3(B_), dim3(128), 0, stream>>>(user_ids, user_emb, out);

  if (ws_size < NEED_FULL) {
    ck_kZ<<<dim3(512), dim3(256), 0, stream>>>(out);
    return;
  }

  hipMemsetAsync(ws, 0, OV_BYTES, stream);  // atomicMax identity (all outputs >= 0)

  ck_kA<<<dim3(B_), dim3(256), 0, stream>>>(item_seq, item_emb, ws);
  ck_kW2<<<dim3(1275), dim3(256), 0, stream>>>(hconv_w, ws);
  ck_kB<<<dim3(B_), dim3(256), 0, stream>>>(item_seq, item_emb, vfilter, ws);
  ck_kC4<<<dim3(64, 8), dim3(512), 0, stream>>>(hconv_b, ws);
  ck_kD<<<dim3(16, 8), dim3(256), 0, stream>>>(fc_w, fc_b, ws, out);
}